// Round 1
// baseline (138.321 us; speedup 1.0000x reference)
//
#include <hip/hip_runtime.h>
#include <hip/hip_bf16.h>

// out[b,t] = cumsum_t( relu(x @ Wh^T + bh) ) + (x @ Wb + bb)
// B=16384, D=1024, T=512. fp32 in/out; GEMM done in bf16 MFMA (fp32 accum).

typedef __bf16 bf16x8 __attribute__((ext_vector_type(8)));
typedef __bf16 bf16x4 __attribute__((ext_vector_type(4)));
typedef float f32x4 __attribute__((ext_vector_type(4)));

typedef const __attribute__((address_space(1))) void* gas_cptr;
typedef __attribute__((address_space(3))) void* las_ptr;

#define BM 64
#define BK 64     // elements; 128 bytes per row in LDS
#define NKIT 16   // 1024 / 64
#define TDIM 512
#define DDIM 1024

// ---- kernel 1: Wh fp32 -> bf16 (512x1024 = 524288 elems, 4/thread) ----
__global__ __launch_bounds__(256) void cvt_wh_kernel(const float* __restrict__ src,
                                                     __bf16* __restrict__ dst) {
    const int i = (blockIdx.x * 256 + threadIdx.x) * 4;
    const float4 v = *reinterpret_cast<const float4*>(src + i);
    bf16x4 o;
    o[0] = (__bf16)v.x; o[1] = (__bf16)v.y; o[2] = (__bf16)v.z; o[3] = (__bf16)v.w;
    *reinterpret_cast<bf16x4*>(dst + i) = o;
}

// ---- kernel 2: fused GEMM + bias + relu + row-cumsum + base add ----
__global__ __launch_bounds__(512, 2) void survival_kernel(
    const float* __restrict__ x,      // [16384][1024] fp32
    const __bf16* __restrict__ Whb,   // [512][1024] bf16 (pre-converted)
    const float* __restrict__ bh,     // [512]
    const float* __restrict__ Wb,     // [1024]
    const float* __restrict__ bbp,    // [1]
    float* __restrict__ out)          // [16384][512] fp32
{
    // LDS: double-buffered A (64 rows x 128B) and B (512 rows x 128B), XOR-swizzled
    __shared__ __align__(16) char Alds[2][BM * 128];      // 16 KB
    __shared__ __align__(16) char Blds[2][TDIM * 128];    // 128 KB
    __shared__ float baseLds[BM];
    __shared__ float totLds[BM][4];

    const int tid  = threadIdx.x;
    const int lane = tid & 63;
    const int wid  = tid >> 6;   // 0..7
    const int wm   = wid >> 2;   // 0..1  (row half: 32 rows)
    const int wn   = wid & 3;    // 0..3  (col quarter: 128 cols)
    const int brow = blockIdx.x * BM;

    const float bb0 = bbp[0];

    // --- A staging map: thread -> (row ar, 8-elem k chunk ak) ---
    const int ar = tid >> 3;            // 0..63
    const int ak = (tid & 7) * 8;       // 0..56
    const float* xrow  = x  + (size_t)(brow + ar) * DDIM + ak;
    const float* wbrow = Wb + ak;
    const int a_swz = ((ar >> 1) & 7) << 4;
    char* const a_dst0 = &Alds[0][0] + ar * 128 + ((ak * 2) ^ a_swz);

    // --- B staging map: per wave 8 global_load_lds calls of 1 KB (8 rows) ---
    const int b_row_lane = wid * 64 + (lane >> 3);   // + c*8
    const int b_byte     = (lane & 7) * 16;

    float bpart = 0.f;
    f32x4 acc[2][8];
#pragma unroll
    for (int rt = 0; rt < 2; ++rt)
#pragma unroll
        for (int n = 0; n < 8; ++n)
            acc[rt][n] = (f32x4){0.f, 0.f, 0.f, 0.f};

    auto stage = [&](int buf, int it) {
        const int k0 = it * BK;
        // B tiles: linear LDS dest, pre-swizzled global source (rule #21)
#pragma unroll
        for (int c = 0; c < 8; ++c) {
            const int row = b_row_lane + c * 8;
            const int kb  = b_byte ^ (((row >> 1) & 7) << 4);     // byte in 128B row
            const __bf16* g = Whb + (size_t)row * DDIM + k0 + (kb >> 1);
            char* l = &Blds[buf][0] + (wid * 64 + c * 8) * 128;   // wave-uniform base
            __builtin_amdgcn_global_load_lds((gas_cptr)(const void*)g,
                                             (las_ptr)(void*)l, 16, 0, 0);
        }
        // A tile: fp32 load, fused base-dot, convert, swizzled ds_write_b128
        const float4 x0 = *reinterpret_cast<const float4*>(xrow + k0);
        const float4 x1 = *reinterpret_cast<const float4*>(xrow + k0 + 4);
        const float4 w0 = *reinterpret_cast<const float4*>(wbrow + k0);
        const float4 w1 = *reinterpret_cast<const float4*>(wbrow + k0 + 4);
        bpart += x0.x * w0.x + x0.y * w0.y + x0.z * w0.z + x0.w * w0.w
               + x1.x * w1.x + x1.y * w1.y + x1.z * w1.z + x1.w * w1.w;
        bf16x8 av;
        av[0] = (__bf16)x0.x; av[1] = (__bf16)x0.y; av[2] = (__bf16)x0.z; av[3] = (__bf16)x0.w;
        av[4] = (__bf16)x1.x; av[5] = (__bf16)x1.y; av[6] = (__bf16)x1.z; av[7] = (__bf16)x1.w;
        *reinterpret_cast<bf16x8*>(a_dst0 + buf * (BM * 128)) = av;
    };

    auto compute = [&](int buf) {
        const char* Ab = &Alds[buf][0];
        const char* Bb = &Blds[buf][0];
#pragma unroll
        for (int h = 0; h < 2; ++h) {
            bf16x8 af[2];
#pragma unroll
            for (int rt = 0; rt < 2; ++rt) {
                const int row  = wm * 32 + rt * 16 + (lane & 15);
                const int slot = h * 4 + (lane >> 4);
                af[rt] = *reinterpret_cast<const bf16x8*>(
                    Ab + row * 128 + ((slot * 16) ^ (((row >> 1) & 7) << 4)));
            }
#pragma unroll
            for (int n = 0; n < 8; ++n) {
                const int trow = wn * 128 + n * 16 + (lane & 15);
                const int slot = h * 4 + (lane >> 4);
                const bf16x8 bfr = *reinterpret_cast<const bf16x8*>(
                    Bb + trow * 128 + ((slot * 16) ^ (((trow >> 1) & 7) << 4)));
                acc[0][n] = __builtin_amdgcn_mfma_f32_16x16x32_bf16(af[0], bfr, acc[0][n], 0, 0, 0);
                acc[1][n] = __builtin_amdgcn_mfma_f32_16x16x32_bf16(af[1], bfr, acc[1][n], 0, 0, 0);
            }
        }
    };

    // --- K loop: double-buffered, one barrier per iter ---
    stage(0, 0);
    __syncthreads();
#pragma unroll 2
    for (int it = 0; it < NKIT; ++it) {
        const int cur = it & 1;
        if (it + 1 < NKIT) stage(cur ^ 1, it + 1);
        compute(cur);
        __syncthreads();
    }

    // --- base = x@Wb + bb : reduce 8 partials per row (same-wave contiguous) ---
    bpart += __shfl_xor(bpart, 1, 8);
    bpart += __shfl_xor(bpart, 2, 8);
    bpart += __shfl_xor(bpart, 4, 8);
    if ((tid & 7) == 0) baseLds[tid >> 3] = bpart + bb0;

    // --- epilogue: bias + relu + in-register inclusive scan over columns ---
    // C layout (m89): col = lane&15, row = (lane>>4)*4 + j  within each 16x16 tile
    float bhv[8];
#pragma unroll
    for (int n = 0; n < 8; ++n)
        bhv[n] = bh[wn * 128 + n * 16 + (lane & 15)];

    float carry[2][4] = {{0.f, 0.f, 0.f, 0.f}, {0.f, 0.f, 0.f, 0.f}};
#pragma unroll
    for (int n = 0; n < 8; ++n) {
#pragma unroll
        for (int rt = 0; rt < 2; ++rt) {
#pragma unroll
            for (int j = 0; j < 4; ++j) {
                float v = fmaxf(acc[rt][n][j] + bhv[n], 0.f);
                // inclusive scan across the 16-lane column segment
#pragma unroll
                for (int off = 1; off < 16; off <<= 1) {
                    const float u = __shfl_up(v, (unsigned)off, 16);
                    if ((lane & 15) >= off) v += u;
                }
                v += carry[rt][j];
                carry[rt][j] = __shfl(v, 15, 16);  // running row total
                acc[rt][n][j] = v;
            }
        }
    }

    // per-row 128-col chunk totals -> LDS for cross-wave carry
    if ((lane & 15) == 0) {
#pragma unroll
        for (int rt = 0; rt < 2; ++rt)
#pragma unroll
            for (int j = 0; j < 4; ++j) {
                const int r = wm * 32 + rt * 16 + (lane >> 4) * 4 + j;
                totLds[r][wn] = carry[rt][j];
            }
    }
    __syncthreads();

#pragma unroll
    for (int rt = 0; rt < 2; ++rt) {
#pragma unroll
        for (int j = 0; j < 4; ++j) {
            const int r = wm * 32 + rt * 16 + (lane >> 4) * 4 + j;
            float rc = baseLds[r];
            if (wn > 0) rc += totLds[r][0];
            if (wn > 1) rc += totLds[r][1];
            if (wn > 2) rc += totLds[r][2];
            float* orow = out + (size_t)(brow + r) * TDIM + wn * 128 + (lane & 15);
#pragma unroll
            for (int n = 0; n < 8; ++n)
                orow[n * 16] = acc[rt][n][j] + rc;
        }
    }
}

extern "C" void kernel_launch(void* const* d_in, const int* in_sizes, int n_in,
                              void* d_out, int out_size, void* d_ws, size_t ws_size,
                              hipStream_t stream) {
    const float* x  = (const float*)d_in[0];  // [16384][1024]
    const float* Wh = (const float*)d_in[1];  // [512][1024]
    const float* bh = (const float*)d_in[2];  // [512]
    const float* Wb = (const float*)d_in[3];  // [1024]
    const float* bb = (const float*)d_in[4];  // [1]
    float* out = (float*)d_out;               // [16384][512]
    __bf16* Whb = (__bf16*)d_ws;              // 1 MB scratch

    // Wh -> bf16 (524288 elems / 4 per thread / 256 per block = 512 blocks)
    cvt_wh_kernel<<<512, 256, 0, stream>>>(Wh, Whb);
    // fused GEMM + cumsum: 16384/64 = 256 blocks of 512 threads
    survival_kernel<<<256, 512, 0, stream>>>(x, Whb, bh, Wb, bb, out);
}